// Round 8
// baseline (90.146 us; speedup 1.0000x reference)
//
#include <hip/hip_runtime.h>
#include <math.h>

namespace {

typedef __bf16 bf16_t;
typedef bf16_t bf16x8 __attribute__((ext_vector_type(8)));
typedef bf16_t bf16x4 __attribute__((ext_vector_type(4)));
typedef float f32x4 __attribute__((ext_vector_type(4)));

constexpr int B = 8, L = 101, DIM = 1024, H = 8, DH = 128, MF = 621, MFP = 640;
constexpr int BL = B * L;    // 808
constexpr int BLP = 832;     // padded rows for GEMM A
constexpr int BH = B * H;    // 64
constexpr int RR = BL * H;   // 6464

constexpr float DN    = 0.29730177875068026f;   // 128^-0.25
constexpr float DN2   = 0.08838834764831845f;   // 128^-0.5
constexpr float RATIO = 0.04012861672f;         // 621^-0.5
constexpr float EPS   = 1e-4f;

// split_all segment sizes (bf16x4 / float4 units)
constexpr int NX = BL * DIM / 4;    // 206848
constexpr int NP = MFP * 32;        // 20480  (proj -> ph only)
constexpr int NR = 64 * DH / 4;     // 2048   (rpe, padded to 64 rows, split)
constexpr int NW = DIM * DIM / 4;   // 262144
constexpr int NZ = 4 * (BLP - BL) * DIM / 4;  // 24576 pad-zero units (xh,xl,qh,ql)
constexpr int NTOT = NX + NP + NR + 3 * NW + NZ;

__device__ __forceinline__ f32x4 mfma16(bf16x8 a, bf16x8 b, f32x4 c) {
  return __builtin_amdgcn_mfma_f32_16x16x32_bf16(a, b, c, 0, 0, 0);
}

__device__ __forceinline__ void split2(float f, bf16_t& h, bf16_t& l) {
  h = (bf16_t)f;
  l = (bf16_t)(f - (float)h);
}

__device__ __forceinline__ void gload_lds16(const bf16_t* g, bf16_t* l) {
  __builtin_amdgcn_global_load_lds(
      (const __attribute__((address_space(1))) void*)g,
      (__attribute__((address_space(3))) void*)l, 16, 0, 0);
}

// ---------- one-shot convert/split of everything ----------
__global__ __launch_bounds__(256) void split_all(const float* __restrict__ x,
                                                 const float* __restrict__ proj,
                                                 const float* __restrict__ rpe,
                                                 const float* __restrict__ Wq,
                                                 const float* __restrict__ Wv,
                                                 const float* __restrict__ Wo,
                                                 bf16_t* __restrict__ xh, bf16_t* __restrict__ xl,
                                                 bf16_t* __restrict__ ph,
                                                 bf16_t* __restrict__ rh, bf16_t* __restrict__ rl,
                                                 bf16_t* __restrict__ Wh,
                                                 bf16_t* __restrict__ Woh, bf16_t* __restrict__ Wol,
                                                 bf16_t* __restrict__ qh, bf16_t* __restrict__ ql) {
  const int u = blockIdx.x * 256 + threadIdx.x;
  if (u >= NTOT) return;
  auto emit2 = [](const float* s4, float sc, bf16_t* dh, bf16_t* dl, size_t off) {
    float4 f = *(const float4*)s4;
    bf16x4 hv, lv; bf16_t h, l;
    split2(f.x * sc, h, l); hv[0] = h; lv[0] = l;
    split2(f.y * sc, h, l); hv[1] = h; lv[1] = l;
    split2(f.z * sc, h, l); hv[2] = h; lv[2] = l;
    split2(f.w * sc, h, l); hv[3] = h; lv[3] = l;
    *(bf16x4*)(dh + off) = hv;
    *(bf16x4*)(dl + off) = lv;
  };
  auto emit1 = [](const float* s4, float sc, bf16_t* dh, size_t off) {
    float4 f = *(const float4*)s4;
    bf16x4 hv;
    hv[0] = (bf16_t)(f.x * sc); hv[1] = (bf16_t)(f.y * sc);
    hv[2] = (bf16_t)(f.z * sc); hv[3] = (bf16_t)(f.w * sc);
    *(bf16x4*)(dh + off) = hv;
  };
  int t = u;
  if (t < NX) { emit2(x + (size_t)t * 4, 1.f, xh, xl, (size_t)t * 4); return; }
  t -= NX;
  if (t < NP) {
    if ((t >> 5) < MF) emit1(proj + (size_t)t * 4, DN, ph, (size_t)t * 4);
    else { bf16x4 z = {}; *(bf16x4*)(ph + (size_t)t * 4) = z; }
    return;
  }
  t -= NP;
  if (t < NR) {
    if (t < 5 * DH / 4) emit2(rpe + (size_t)t * 4, 1.f, rh, rl, (size_t)t * 4);
    else { bf16x4 z = {}; *(bf16x4*)(rh + (size_t)t * 4) = z; *(bf16x4*)(rl + (size_t)t * 4) = z; }
    return;
  }
  t -= NR;
  if (t < NW) { emit1(Wq + (size_t)t * 4, 1.f, Wh, (size_t)t * 4); return; }
  t -= NW;
  if (t < NW) { emit1(Wv + (size_t)t * 4, 1.f, Wh, (size_t)(t + NW) * 4); return; }
  t -= NW;
  if (t < NW) { emit2(Wo + (size_t)t * 4, 1.f, Woh, Wol, (size_t)t * 4); return; }
  t -= NW;
  {  // zero pads rows 808..831 of xh,xl,qh,ql
    const int buf = t / 6144, o = t % 6144;
    bf16_t* dst = (buf == 0) ? xh : (buf == 1) ? xl : (buf == 2) ? qh : ql;
    bf16x4 z = {};
    *(bf16x4*)(dst + (size_t)BL * DIM + (size_t)o * 4) = z;
  }
}

// ---------- LDS-staged split-bf16 MFMA GEMM, tile 32x64, 4 waves of 16x32 ----------
// TERMS==2: C = (Ah+Al)Bh.  TERMS==3: C = AhBh + AlBh + AhBl.
// MODE 0: f32 out + bias0, stride 1024, row guard <808 (o-proj).
// MODE 1: qv — col<1024 -> bf16 split q (bias0); col>=1024 -> f32 v (bias1); guard <808.
// MODE 2: dd — f32 out stride 640, no bias; blockIdx.y>=202 -> rf rows (Rh/Rl),
//         output rows RR + (y-202)*32.
template<int MODE, int TERMS, int KK>
__global__ __launch_bounds__(256) void gemm32(const bf16_t* __restrict__ Ah,
                                              const bf16_t* __restrict__ Al,
                                              const bf16_t* __restrict__ Rh,
                                              const bf16_t* __restrict__ Rl,
                                              const bf16_t* __restrict__ Bh,
                                              const bf16_t* __restrict__ Bl,
                                              const float* __restrict__ bias0,
                                              const float* __restrict__ bias1,
                                              float* __restrict__ Cf,
                                              bf16_t* __restrict__ Ch,
                                              bf16_t* __restrict__ Cl) {
  constexpr int NK = KK / 32;
  constexpr int NBT = (TERMS == 2) ? 1 : 2;
  __shared__ bf16_t ldsA[2][2][32 * 32];
  __shared__ bf16_t ldsB[2][NBT][64 * 32];
  const int tid = threadIdx.x;
  const int w = tid >> 6, lane = tid & 63;
  const int wr = w >> 1, wc = w & 1;
  const int l15 = lane & 15, l4 = lane >> 4;
  int rowBase = blockIdx.y * 32;
  int outRow0 = rowBase;
  const bf16_t* Asrc_h = Ah;
  const bf16_t* Asrc_l = Al;
  if (MODE == 2 && blockIdx.y >= 202) {
    rowBase = (blockIdx.y - 202) * 32;
    outRow0 = RR + rowBase;
    Asrc_h = Rh; Asrc_l = Rl;
  }
  const int colBase = blockIdx.x * 64;
  // staging: wave-uniform hoisted source pointer (R4 idiom)
  const int r4 = lane >> 2;
  const int cs = (lane & 3) ^ (r4 & 3);
  const bf16_t* src;
  int grow0, dstB = 0;
  if (TERMS == 2) {
    src = (w == 0) ? Asrc_h : (w == 1) ? Asrc_l : Bh;
    grow0 = (w < 2) ? rowBase : colBase + ((w == 3) ? 32 : 0);
    dstB = (w == 3) ? 1024 : 0;
  } else {
    src = (w == 0) ? Asrc_h : (w == 1) ? Asrc_l : (w == 2) ? Bh : Bl;
    grow0 = (w < 2) ? rowBase : colBase;
  }
  const bf16_t* srcL = src + (size_t)(grow0 + r4) * KK + cs * 8;
  auto STAGE = [&](int bf, int k0) {
    if (w < 2) {
#pragma unroll
      for (int j = 0; j < 2; ++j)
        gload_lds16(srcL + (size_t)(16 * j) * KK + k0, &ldsA[bf][w][j * 512]);
    } else if (TERMS == 2) {
#pragma unroll
      for (int j = 0; j < 2; ++j)
        gload_lds16(srcL + (size_t)(16 * j) * KK + k0, &ldsB[bf][0][dstB + j * 512]);
    } else {
#pragma unroll
      for (int j = 0; j < 4; ++j)
        gload_lds16(srcL + (size_t)(16 * j) * KK + k0, &ldsB[bf][w - 2][j * 512]);
    }
  };
  // ds_read addresses (swizzled)
  const int cX = (l4 ^ (l15 & 3)) * 8;
  const int aoff = (wr * 16 + l15) * 32 + cX;
  const int boff0 = (wc * 32 + l15) * 32 + cX, boff1 = boff0 + 16 * 32;
  f32x4 acc[2] = {};
  STAGE(0, 0);
  __syncthreads();
  int bf = 0;
  for (int ks = 0; ks < NK; ++ks) {
    if (ks + 1 < NK) STAGE(bf ^ 1, (ks + 1) * 32);
    bf16x8 a_h = *(const bf16x8*)&ldsA[bf][0][aoff];
    bf16x8 a_l = *(const bf16x8*)&ldsA[bf][1][aoff];
    bf16x8 b0h = *(const bf16x8*)&ldsB[bf][0][boff0];
    bf16x8 b1h = *(const bf16x8*)&ldsB[bf][0][boff1];
    acc[0] = mfma16(a_h, b0h, acc[0]);
    acc[0] = mfma16(a_l, b0h, acc[0]);
    acc[1] = mfma16(a_h, b1h, acc[1]);
    acc[1] = mfma16(a_l, b1h, acc[1]);
    if (TERMS == 3) {
      bf16x8 b0l = *(const bf16x8*)&ldsB[bf][1][boff0];
      bf16x8 b1l = *(const bf16x8*)&ldsB[bf][1][boff1];
      acc[0] = mfma16(a_h, b0l, acc[0]);
      acc[1] = mfma16(a_h, b1l, acc[1]);
    }
    __syncthreads();
    bf ^= 1;
  }
#pragma unroll
  for (int ni = 0; ni < 2; ++ni) {
    const int col = colBase + wc * 32 + ni * 16 + l15;
#pragma unroll
    for (int r2 = 0; r2 < 4; ++r2) {
      const int row = outRow0 + wr * 16 + l4 * 4 + r2;
      if (MODE == 2) {
        Cf[(size_t)row * MFP + col] = acc[ni][r2];
      } else if (row < BL) {
        if (MODE == 0) {
          Cf[(size_t)row * 1024 + col] = acc[ni][r2] + bias0[col];
        } else {
          if (col < 1024) {
            float val = acc[ni][r2] + bias0[col];
            bf16_t h, lo; split2(val, h, lo);
            Ch[(size_t)row * 1024 + col] = h;
            Cl[(size_t)row * 1024 + col] = lo;
          } else {
            Cf[(size_t)row * 1024 + (col - 1024)] = acc[ni][r2] + bias1[col - 1024];
          }
        }
      }
    }
  }
}

// ---------- qf2: row-max + exp + 5 reductions over dd; blocks >= 808 do vsum ----------
__global__ __launch_bounds__(256) void qf2_kernel(const float* __restrict__ dd,
                                                  const bf16_t* __restrict__ qh,
                                                  const bf16_t* __restrict__ ql,
                                                  const float* __restrict__ rpe,
                                                  const float* __restrict__ v,
                                                  float* __restrict__ vsum,
                                                  float* __restrict__ fd) {
  const int tid = threadIdx.x;
  if (blockIdx.x >= 808) {   // vsum blocks: 32 blocks x 2 bh each
    const int bi = blockIdx.x - 808;
    const int half = tid >> 7, d = tid & 127;
    const int bh = bi * 2 + half;
    const int b = bh >> 3, h = bh & 7;
    const float* base = v + (size_t)(b * L) * DIM + h * DH + d;
    float s0 = 0.f, s1 = 0.f, s2 = 0.f, s3 = 0.f;
    int l = 0;
    for (; l + 4 <= L; l += 4) {
      s0 += base[(size_t)l * DIM];
      s1 += base[(size_t)(l + 1) * DIM];
      s2 += base[(size_t)(l + 2) * DIM];
      s3 += base[(size_t)(l + 3) * DIM];
    }
    for (; l < L; ++l) s0 += base[(size_t)l * DIM];
    vsum[(size_t)bh * DH + d] = s0 + s1 + s2 + s3;
    return;
  }
  __shared__ float rfs[5][MFP];
  __shared__ float diag5v[8];
  __shared__ float redmx[4];
  const int w = tid >> 6, lane = tid & 63;
  if (tid < 40) {  // diag5v[r] = 0.5*DN^2*|rpe_r|^2
    const int row = tid >> 3, ch = tid & 7;
    float s = 0.f;
#pragma unroll
    for (int e = 0; e < 16; ++e) { float f = rpe[row * DH + ch * 16 + e]; s += f * f; }
    s += __shfl_xor(s, 1, 64); s += __shfl_xor(s, 2, 64); s += __shfl_xor(s, 4, 64);
    if (ch == 0) diag5v[row] = (0.5f * DN2) * s;
  }
  // stage rf dd rows + global rf max
  float pmax = -3.4e38f;
  for (int i = tid; i < 5 * MFP; i += 256) {
    const int r = i / MFP, c = i % MFP;
    float vv = dd[(size_t)(RR + r) * MFP + c];
    rfs[r][c] = vv;
    if (c < MF) pmax = fmaxf(pmax, vv);
  }
#pragma unroll
  for (int m = 1; m <= 32; m <<= 1) pmax = fmaxf(pmax, __shfl_xor(pmax, m, 64));
  if (lane == 0) redmx[w] = pmax;
  __syncthreads();
  const float mxR = fmaxf(fmaxf(redmx[0], redmx[1]), fmaxf(redmx[2], redmx[3]));
  for (int i = tid; i < 5 * MFP; i += 256) {
    const int r = i / MFP, c = i % MFP;
    rfs[r][c] = (c < MF) ? RATIO * (__expf(rfs[r][c] - diag5v[r] - mxR) + EPS) : 0.f;
  }
  __syncthreads();
  for (int i = tid; i < 4 * MFP; i += 256) rfs[i / MFP][i % MFP] -= rfs[4][i % MFP];
  __syncthreads();
  // q rows
  const int rbase = blockIdx.x * 8;
#pragma unroll
  for (int rr = 0; rr < 2; ++rr) {
    const int r = rbase + w * 2 + rr;
    const float* row = dd + (size_t)r * MFP;
    float vv[10];
#pragma unroll
    for (int t = 0; t < 10; ++t) vv[t] = row[lane + 64 * t];
    float m = -3.4e38f;
#pragma unroll
    for (int t = 0; t < 10; ++t) if (lane + 64 * t < MF) m = fmaxf(m, vv[t]);
#pragma unroll
    for (int mk = 1; mk <= 32; mk <<= 1) m = fmaxf(m, __shfl_xor(m, mk, 64));
    float d0 = (float)qh[(size_t)r * DH + lane] + (float)ql[(size_t)r * DH + lane];
    float d1 = (float)qh[(size_t)r * DH + 64 + lane] + (float)ql[(size_t)r * DH + 64 + lane];
    float dsq = d0 * d0 + d1 * d1;
#pragma unroll
    for (int mk = 1; mk <= 32; mk <<= 1) dsq += __shfl_xor(dsq, mk, 64);
    const float sub = (0.5f * DN2) * dsq + m;
    float s0 = 0, s1 = 0, s2 = 0, s3 = 0, s4 = 0;
#pragma unroll
    for (int t = 0; t < 10; ++t) {
      const int c = lane + 64 * t;
      const float qfv = RATIO * (__expf(vv[t] - sub) + EPS);
      s0 += qfv * rfs[0][c]; s1 += qfv * rfs[1][c]; s2 += qfv * rfs[2][c];
      s3 += qfv * rfs[3][c]; s4 += qfv * rfs[4][c];
    }
#pragma unroll
    for (int mk = 1; mk <= 32; mk <<= 1) {
      s0 += __shfl_xor(s0, mk, 64); s1 += __shfl_xor(s1, mk, 64);
      s2 += __shfl_xor(s2, mk, 64); s3 += __shfl_xor(s3, mk, 64);
      s4 += __shfl_xor(s4, mk, 64);
    }
    if (lane == 0) {
      float* f = fd + (size_t)r * 8;
      f[0] = s0; f[1] = s1; f[2] = s2; f[3] = s3; f[4] = s4;
    }
  }
}

// ---------- gather + normalize + bf16-split of attn ----------
__global__ __launch_bounds__(256) void out_kernel(const float* __restrict__ fd,
                                                  const float* __restrict__ v,
                                                  const float* __restrict__ vsum,
                                                  bf16_t* __restrict__ attnh,
                                                  bf16_t* __restrict__ attnl) {
  const int tid = threadIdx.x;
  const int sub = tid >> 7, d = tid & 127;
  const int bh = blockIdx.y, b = bh >> 3, h = bh & 7;
  const int l = blockIdx.x * 2 + sub;
  if (l >= L) return;
  const size_t r = (size_t)(b * L + l) * H + h;
  const float q0 = fd[r * 8 + 0], q1 = fd[r * 8 + 1], q2 = fd[r * 8 + 2],
              q3 = fd[r * 8 + 3], sM = fd[r * 8 + 4];
  float o = sM * vsum[(size_t)bh * DH + d];
  float c0 = 0, c1 = 0, c2 = 0, c3 = 0;
  const int xo = (l < 100) ? (l % 10) : 0;
  const int yo = (l < 100) ? (l / 10) : 10;
#pragma unroll
  for (int k = 0; k < 49; ++k) {
    const int dx = (k % 7) - 3, dy = (k / 7) - 3;
    const int xp = xo + dx, yp = yo + dy;
    const int df = (dx < 0 ? -dx : dx) + (dy < 0 ? -dy : dy);
    if (xp >= 0 && xp < 10 && yp >= 0 && yp < 10 && df < 4) {
      float qq;
      if (df == 0)      { c0 += 1.f; qq = q0; }
      else if (df == 1) { c1 += 1.f; qq = q1; }
      else if (df == 2) { c2 += 1.f; qq = q2; }
      else              { c3 += 1.f; qq = q3; }
      const int pos = l + dx + 10 * dy;
      o += qq * v[(size_t)(b * L + pos) * DIM + h * DH + d];
    }
  }
  const float D = c0 * q0 + c1 * q1 + c2 * q2 + c3 * q3 + (float)L * sM;
  const float val = o / D;
  bf16_t hi, lo; split2(val, hi, lo);
  const size_t oi = (size_t)(b * L + l) * DIM + h * DH + d;
  attnh[oi] = hi;
  attnl[oi] = lo;
}

}  // namespace

extern "C" void kernel_launch(void* const* d_in, const int* in_sizes, int n_in,
                              void* d_out, int out_size, void* d_ws, size_t ws_size,
                              hipStream_t stream) {
  const float* x    = (const float*)d_in[0];
  const float* Wq   = (const float*)d_in[1];
  const float* bq   = (const float*)d_in[2];
  const float* Wv   = (const float*)d_in[3];
  const float* bv   = (const float*)d_in[4];
  const float* rpe  = (const float*)d_in[5];
  const float* proj = (const float*)d_in[6];
  const float* Wo   = (const float*)d_in[7];
  const float* bo   = (const float*)d_in[8];

  char* p = (char*)d_ws;
  auto alloc = [&](size_t bytes) { char* r = p; p += (bytes + 255) & ~255ull; return r; };
  bf16_t* xh  = (bf16_t*)alloc((size_t)BLP * DIM * 2);
  bf16_t* xl  = (bf16_t*)alloc((size_t)BLP * DIM * 2);
  bf16_t* Wh  = (bf16_t*)alloc((size_t)2 * DIM * DIM * 2);  // Wq rows 0..1023, Wv rows 1024..2047
  bf16_t* Woh = (bf16_t*)alloc((size_t)DIM * DIM * 2);
  bf16_t* Wol = (bf16_t*)alloc((size_t)DIM * DIM * 2);
  bf16_t* ph  = (bf16_t*)alloc((size_t)MFP * DH * 2);
  bf16_t* rh  = (bf16_t*)alloc((size_t)64 * DH * 2);
  bf16_t* rl  = (bf16_t*)alloc((size_t)64 * DH * 2);
  bf16_t* qh  = (bf16_t*)alloc((size_t)BLP * DIM * 2);   // q, later attn
  bf16_t* ql  = (bf16_t*)alloc((size_t)BLP * DIM * 2);
  float*  v   = (float*)alloc((size_t)BL * DIM * 4);
  float*  dd  = (float*)alloc((size_t)(RR + 64) * MFP * 4);
  float*  fd  = (float*)alloc((size_t)RR * 8 * 4);
  float*  vsm = (float*)alloc((size_t)BH * DH * 4);

  split_all<<<(NTOT + 255) / 256, 256, 0, stream>>>(x, proj, rpe, Wq, Wv, Wo,
                                                    xh, xl, ph, rh, rl,
                                                    Wh, Woh, Wol, qh, ql);
  // fused q+v projection: N=2048, 2-term, tile 32x64 (832 blocks)
  gemm32<1, 2, 1024><<<dim3(32, 26), 256, 0, stream>>>(xh, xl, nullptr, nullptr,
                                                       Wh, nullptr, bq, bv,
                                                       v, qh, ql);
  // dd GEMM: 2-term, K=128, tile 32x64 (2040 blocks); y>=202 -> rf rows
  gemm32<2, 2, 128><<<dim3(10, 204), 256, 0, stream>>>(qh, ql, rh, rl,
                                                       ph, nullptr, nullptr, nullptr,
                                                       dd, nullptr, nullptr);
  qf2_kernel<<<808 + 32, 256, 0, stream>>>(dd, qh, ql, rpe, v, vsm, fd);
  out_kernel<<<dim3((L + 1) / 2, BH), 256, 0, stream>>>(fd, v, vsm, qh, ql);
  // output projection: 3-term, tile 32x64 (416 blocks)
  gemm32<0, 3, 1024><<<dim3(16, 26), 256, 0, stream>>>(qh, ql, nullptr, nullptr,
                                                       Woh, Wol, bo, nullptr,
                                                       (float*)d_out, nullptr, nullptr);
}

// Round 9
// 85.085 us; speedup vs baseline: 1.0595x; 1.0595x over previous
//
#include <hip/hip_runtime.h>
#include <math.h>

namespace {

typedef __bf16 bf16_t;
typedef bf16_t bf16x8 __attribute__((ext_vector_type(8)));
typedef bf16_t bf16x4 __attribute__((ext_vector_type(4)));
typedef float f32x4 __attribute__((ext_vector_type(4)));

constexpr int B = 8, L = 101, DIM = 1024, H = 8, DH = 128, MF = 621, MFP = 640;
constexpr int BL = B * L;    // 808
constexpr int BLP = 832;     // padded rows for GEMM A
constexpr int BH = B * H;    // 64
constexpr int RR = BL * H;   // 6464

constexpr float DN    = 0.29730177875068026f;   // 128^-0.25
constexpr float DN2   = 0.08838834764831845f;   // 128^-0.5
constexpr float RATIO = 0.04012861672f;         // 621^-0.5
constexpr float EPS   = 1e-4f;

// split_all segment sizes (bf16x4 / float4 units)
constexpr int NX = BL * DIM / 4;    // 206848
constexpr int NP = MFP * 32;        // 20480  (proj -> ph only)
constexpr int NR = 64 * DH / 4;     // 2048   (rpe, padded to 64 rows, split)
constexpr int NW = DIM * DIM / 4;   // 262144
constexpr int NZ = 4 * (BLP - BL) * DIM / 4;  // 24576 pad-zero units (xh,xl,qh,ql)
constexpr int NTOT = NX + NP + NR + 3 * NW + NZ;

__device__ __forceinline__ f32x4 mfma16(bf16x8 a, bf16x8 b, f32x4 c) {
  return __builtin_amdgcn_mfma_f32_16x16x32_bf16(a, b, c, 0, 0, 0);
}

__device__ __forceinline__ void split2(float f, bf16_t& h, bf16_t& l) {
  h = (bf16_t)f;
  l = (bf16_t)(f - (float)h);
}

__device__ __forceinline__ void gload_lds16(const bf16_t* g, bf16_t* l) {
  __builtin_amdgcn_global_load_lds(
      (const __attribute__((address_space(1))) void*)g,
      (__attribute__((address_space(3))) void*)l, 16, 0, 0);
}

// ---------- one-shot convert/split of everything ----------
__global__ __launch_bounds__(256) void split_all(const float* __restrict__ x,
                                                 const float* __restrict__ proj,
                                                 const float* __restrict__ rpe,
                                                 const float* __restrict__ Wq,
                                                 const float* __restrict__ Wv,
                                                 const float* __restrict__ Wo,
                                                 bf16_t* __restrict__ xh, bf16_t* __restrict__ xl,
                                                 bf16_t* __restrict__ ph,
                                                 bf16_t* __restrict__ rh, bf16_t* __restrict__ rl,
                                                 bf16_t* __restrict__ Wh,
                                                 bf16_t* __restrict__ Woh,
                                                 bf16_t* __restrict__ qh, bf16_t* __restrict__ ql) {
  const int u = blockIdx.x * 256 + threadIdx.x;
  if (u >= NTOT) return;
  auto emit2 = [](const float* s4, float sc, bf16_t* dh, bf16_t* dl, size_t off) {
    float4 f = *(const float4*)s4;
    bf16x4 hv, lv; bf16_t h, l;
    split2(f.x * sc, h, l); hv[0] = h; lv[0] = l;
    split2(f.y * sc, h, l); hv[1] = h; lv[1] = l;
    split2(f.z * sc, h, l); hv[2] = h; lv[2] = l;
    split2(f.w * sc, h, l); hv[3] = h; lv[3] = l;
    *(bf16x4*)(dh + off) = hv;
    *(bf16x4*)(dl + off) = lv;
  };
  auto emit1 = [](const float* s4, float sc, bf16_t* dh, size_t off) {
    float4 f = *(const float4*)s4;
    bf16x4 hv;
    hv[0] = (bf16_t)(f.x * sc); hv[1] = (bf16_t)(f.y * sc);
    hv[2] = (bf16_t)(f.z * sc); hv[3] = (bf16_t)(f.w * sc);
    *(bf16x4*)(dh + off) = hv;
  };
  int t = u;
  if (t < NX) { emit2(x + (size_t)t * 4, 1.f, xh, xl, (size_t)t * 4); return; }
  t -= NX;
  if (t < NP) {
    if ((t >> 5) < MF) emit1(proj + (size_t)t * 4, DN, ph, (size_t)t * 4);
    else { bf16x4 z = {}; *(bf16x4*)(ph + (size_t)t * 4) = z; }
    return;
  }
  t -= NP;
  if (t < NR) {
    if (t < 5 * DH / 4) emit2(rpe + (size_t)t * 4, 1.f, rh, rl, (size_t)t * 4);
    else { bf16x4 z = {}; *(bf16x4*)(rh + (size_t)t * 4) = z; *(bf16x4*)(rl + (size_t)t * 4) = z; }
    return;
  }
  t -= NR;
  if (t < NW) { emit1(Wq + (size_t)t * 4, 1.f, Wh, (size_t)t * 4); return; }
  t -= NW;
  if (t < NW) { emit1(Wv + (size_t)t * 4, 1.f, Wh, (size_t)(t + NW) * 4); return; }
  t -= NW;
  if (t < NW) { emit1(Wo + (size_t)t * 4, 1.f, Woh, (size_t)t * 4); return; }
  t -= NW;
  {  // zero pads rows 808..831 of xh,xl,qh,ql
    const int buf = t / 6144, o = t % 6144;
    bf16_t* dst = (buf == 0) ? xh : (buf == 1) ? xl : (buf == 2) ? qh : ql;
    bf16x4 z = {};
    *(bf16x4*)(dst + (size_t)BL * DIM + (size_t)o * 4) = z;
  }
}

// ---------- BK=64 LDS-staged 2-term MFMA GEMM, block tile 64x64, 4 waves 32x32 ----------
// C = (Ah+Al) @ Bh^T.  Layout: LDS tile row = 64 bf16 (128 B); col16-group p stores
// logical k-group (p ^ (row&7)) — same involution on gload source and ds_read.
// MODE 0: f32 out + bias0, guard row<808 (o-proj).
// MODE 1: qv — col<1024 -> bf16 split (bias0); col>=1024 -> f32 v (bias1); guard.
template<int MODE>
__global__ __launch_bounds__(256) void gemm64(const bf16_t* __restrict__ Ah,
                                              const bf16_t* __restrict__ Al,
                                              const bf16_t* __restrict__ Bh,
                                              const float* __restrict__ bias0,
                                              const float* __restrict__ bias1,
                                              float* __restrict__ Cf,
                                              bf16_t* __restrict__ Ch,
                                              bf16_t* __restrict__ Cl) {
  constexpr int K = 1024, BK = 64, NK = K / BK;   // 16 steps
  __shared__ bf16_t lds[2][3][64 * 64];           // [dbuf][Ah,Al,B]
  const int tid = threadIdx.x;
  const int w = tid >> 6, lane = tid & 63;
  const int wr = w >> 1, wc = w & 1;
  const int l15 = lane & 15, l4 = lane >> 4;
  const int rowBase = blockIdx.y * 64, colBase = blockIdx.x * 64;
  // staging: w0->Ah(64 rows), w1->Al(64), w2->B rows 0..31, w3->B rows 32..63
  const int r8 = lane >> 3;                 // 0..7
  const int cs = (lane & 7) ^ r8;           // pre-swizzled source col16 group
  const bf16_t* src = (w == 0) ? Ah : (w == 1) ? Al : Bh;
  const int grow0 = (w < 2) ? rowBase : colBase + ((w == 3) ? 32 : 0);
  const bf16_t* srcL = src + (size_t)(grow0 + r8) * K + cs * 8;
  const int tt = (w < 2) ? w : 2;
  const int dst0 = (w == 3) ? 32 * 64 : 0;
  auto STAGE = [&](int bf, int k0) {
    if (w < 2) {
#pragma unroll
      for (int j = 0; j < 8; ++j)
        gload_lds16(srcL + (size_t)(8 * j) * K + k0, &lds[bf][tt][j * 512]);
    } else {
#pragma unroll
      for (int j = 0; j < 4; ++j)
        gload_lds16(srcL + (size_t)(8 * j) * K + k0, &lds[bf][2][dst0 + j * 512]);
    }
  };
  const int ra0 = wr * 32 + l15, ra1 = ra0 + 16;
  const int rb0 = wc * 32 + l15, rb1 = rb0 + 16;
  auto TADDR = [](int row, int kg) { return row * 64 + (((kg) ^ (row & 7)) << 3); };
  f32x4 acc[2][2] = {};
  STAGE(0, 0);
  __syncthreads();
  int bf = 0;
  for (int ks = 0; ks < NK; ++ks) {
    if (ks + 1 < NK) STAGE(bf ^ 1, (ks + 1) * BK);
#pragma unroll
    for (int subk = 0; subk < 2; ++subk) {
      const int kg = subk * 4 + l4;
      bf16x8 a0h = *(const bf16x8*)&lds[bf][0][TADDR(ra0, kg)];
      bf16x8 a0l = *(const bf16x8*)&lds[bf][1][TADDR(ra0, kg)];
      bf16x8 a1h = *(const bf16x8*)&lds[bf][0][TADDR(ra1, kg)];
      bf16x8 a1l = *(const bf16x8*)&lds[bf][1][TADDR(ra1, kg)];
      bf16x8 b0  = *(const bf16x8*)&lds[bf][2][TADDR(rb0, kg)];
      bf16x8 b1  = *(const bf16x8*)&lds[bf][2][TADDR(rb1, kg)];
      acc[0][0] = mfma16(a0h, b0, acc[0][0]);
      acc[0][0] = mfma16(a0l, b0, acc[0][0]);
      acc[0][1] = mfma16(a0h, b1, acc[0][1]);
      acc[0][1] = mfma16(a0l, b1, acc[0][1]);
      acc[1][0] = mfma16(a1h, b0, acc[1][0]);
      acc[1][0] = mfma16(a1l, b0, acc[1][0]);
      acc[1][1] = mfma16(a1h, b1, acc[1][1]);
      acc[1][1] = mfma16(a1l, b1, acc[1][1]);
    }
    __syncthreads();
    bf ^= 1;
  }
#pragma unroll
  for (int ni = 0; ni < 2; ++ni) {
    const int col = colBase + wc * 32 + ni * 16 + l15;
#pragma unroll
    for (int mi = 0; mi < 2; ++mi) {
#pragma unroll
      for (int r2 = 0; r2 < 4; ++r2) {
        const int row = rowBase + wr * 32 + mi * 16 + l4 * 4 + r2;
        if (row < BL) {
          if (MODE == 0) {
            Cf[(size_t)row * 1024 + col] = acc[mi][ni][r2] + bias0[col];
          } else {
            if (col < 1024) {
              float val = acc[mi][ni][r2] + bias0[col];
              bf16_t h, lo; split2(val, h, lo);
              Ch[(size_t)row * 1024 + col] = h;
              Cl[(size_t)row * 1024 + col] = lo;
            } else {
              Cf[(size_t)row * 1024 + (col - 1024)] = acc[mi][ni][r2] + bias1[col - 1024];
            }
          }
        }
      }
    }
  }
}

// ---------- dd GEMM (2-term, tile 32x64, K=128): dd[6464+64][640] ----------
__global__ __launch_bounds__(256) void dd_gemm(const bf16_t* __restrict__ Ah,
                                               const bf16_t* __restrict__ Al,
                                               const bf16_t* __restrict__ Rh,
                                               const bf16_t* __restrict__ Rl,
                                               const bf16_t* __restrict__ Bh,
                                               float* __restrict__ dd) {
  constexpr int KK = 128, NK = 4;
  __shared__ bf16_t ldsA[2][2][32 * 32];
  __shared__ bf16_t ldsB[2][64 * 32];
  const int tid = threadIdx.x;
  const int w = tid >> 6, lane = tid & 63;
  const int wr = w >> 1, wc = w & 1;
  const int l15 = lane & 15, l4 = lane >> 4;
  int rowBase = blockIdx.y * 32;
  int outRow0 = rowBase;
  const bf16_t* Asrc_h = Ah;
  const bf16_t* Asrc_l = Al;
  if (blockIdx.y >= 202) {
    rowBase = (blockIdx.y - 202) * 32;
    outRow0 = RR + rowBase;
    Asrc_h = Rh; Asrc_l = Rl;
  }
  const int colBase = blockIdx.x * 64;
  const int r4 = lane >> 2;
  const int cs = (lane & 3) ^ (r4 & 3);
  const bf16_t* src = (w == 0) ? Asrc_h : (w == 1) ? Asrc_l : Bh;
  const int grow0 = (w < 2) ? rowBase : colBase + ((w == 3) ? 32 : 0);
  const int dstB = (w == 3) ? 1024 : 0;
  const bf16_t* srcL = src + (size_t)(grow0 + r4) * KK + cs * 8;
  auto STAGE = [&](int bf, int k0) {
    if (w < 2) {
#pragma unroll
      for (int j = 0; j < 2; ++j)
        gload_lds16(srcL + (size_t)(16 * j) * KK + k0, &ldsA[bf][w][j * 512]);
    } else {
#pragma unroll
      for (int j = 0; j < 2; ++j)
        gload_lds16(srcL + (size_t)(16 * j) * KK + k0, &ldsB[bf][dstB + j * 512]);
    }
  };
  const int cX = (l4 ^ (l15 & 3)) * 8;
  const int aoff = (wr * 16 + l15) * 32 + cX;
  const int boff0 = (wc * 32 + l15) * 32 + cX, boff1 = boff0 + 16 * 32;
  f32x4 acc[2] = {};
  STAGE(0, 0);
  __syncthreads();
  int bf = 0;
#pragma unroll
  for (int ks = 0; ks < NK; ++ks) {
    if (ks + 1 < NK) STAGE(bf ^ 1, (ks + 1) * 32);
    bf16x8 a_h = *(const bf16x8*)&ldsA[bf][0][aoff];
    bf16x8 a_l = *(const bf16x8*)&ldsA[bf][1][aoff];
    bf16x8 b0 = *(const bf16x8*)&ldsB[bf][boff0];
    bf16x8 b1 = *(const bf16x8*)&ldsB[bf][boff1];
    acc[0] = mfma16(a_h, b0, acc[0]);
    acc[0] = mfma16(a_l, b0, acc[0]);
    acc[1] = mfma16(a_h, b1, acc[1]);
    acc[1] = mfma16(a_l, b1, acc[1]);
    __syncthreads();
    bf ^= 1;
  }
#pragma unroll
  for (int ni = 0; ni < 2; ++ni) {
    const int col = colBase + wc * 32 + ni * 16 + l15;
#pragma unroll
    for (int r2 = 0; r2 < 4; ++r2) {
      const int row = outRow0 + wr * 16 + l4 * 4 + r2;
      dd[(size_t)row * MFP + col] = acc[ni][r2];
    }
  }
}

// ---------- qf2: row-max + exp + 5 reductions over dd; blocks >= 808 do vsum ----------
__global__ __launch_bounds__(256) void qf2_kernel(const float* __restrict__ dd,
                                                  const bf16_t* __restrict__ qh,
                                                  const bf16_t* __restrict__ ql,
                                                  const float* __restrict__ rpe,
                                                  const float* __restrict__ v,
                                                  float* __restrict__ vsum,
                                                  float* __restrict__ fd) {
  const int tid = threadIdx.x;
  if (blockIdx.x >= 808) {   // vsum blocks: 32 blocks x 2 bh each
    const int bi = blockIdx.x - 808;
    const int half = tid >> 7, d = tid & 127;
    const int bh = bi * 2 + half;
    const int b = bh >> 3, h = bh & 7;
    const float* base = v + (size_t)(b * L) * DIM + h * DH + d;
    float s0 = 0.f, s1 = 0.f, s2 = 0.f, s3 = 0.f;
    int l = 0;
    for (; l + 4 <= L; l += 4) {
      s0 += base[(size_t)l * DIM];
      s1 += base[(size_t)(l + 1) * DIM];
      s2 += base[(size_t)(l + 2) * DIM];
      s3 += base[(size_t)(l + 3) * DIM];
    }
    for (; l < L; ++l) s0 += base[(size_t)l * DIM];
    vsum[(size_t)bh * DH + d] = s0 + s1 + s2 + s3;
    return;
  }
  __shared__ float rfs[5][MFP];
  __shared__ float diag5v[8];
  __shared__ float redmx[4];
  const int w = tid >> 6, lane = tid & 63;
  if (tid < 40) {  // diag5v[r] = 0.5*DN^2*|rpe_r|^2
    const int row = tid >> 3, ch = tid & 7;
    float s = 0.f;
#pragma unroll
    for (int e = 0; e < 16; ++e) { float f = rpe[row * DH + ch * 16 + e]; s += f * f; }
    s += __shfl_xor(s, 1, 64); s += __shfl_xor(s, 2, 64); s += __shfl_xor(s, 4, 64);
    if (ch == 0) diag5v[row] = (0.5f * DN2) * s;
  }
  // stage rf dd rows + global rf max
  float pmax = -3.4e38f;
  for (int i = tid; i < 5 * MFP; i += 256) {
    const int r = i / MFP, c = i % MFP;
    float vv = dd[(size_t)(RR + r) * MFP + c];
    rfs[r][c] = vv;
    if (c < MF) pmax = fmaxf(pmax, vv);
  }
#pragma unroll
  for (int m = 1; m <= 32; m <<= 1) pmax = fmaxf(pmax, __shfl_xor(pmax, m, 64));
  if (lane == 0) redmx[w] = pmax;
  __syncthreads();
  const float mxR = fmaxf(fmaxf(redmx[0], redmx[1]), fmaxf(redmx[2], redmx[3]));
  for (int i = tid; i < 5 * MFP; i += 256) {
    const int r = i / MFP, c = i % MFP;
    rfs[r][c] = (c < MF) ? RATIO * (__expf(rfs[r][c] - diag5v[r] - mxR) + EPS) : 0.f;
  }
  __syncthreads();
  for (int i = tid; i < 4 * MFP; i += 256) rfs[i / MFP][i % MFP] -= rfs[4][i % MFP];
  __syncthreads();
  // q rows
  const int rbase = blockIdx.x * 8;
#pragma unroll
  for (int rr = 0; rr < 2; ++rr) {
    const int r = rbase + w * 2 + rr;
    const float* row = dd + (size_t)r * MFP;
    float vv[10];
#pragma unroll
    for (int t = 0; t < 10; ++t) vv[t] = row[lane + 64 * t];
    float m = -3.4e38f;
#pragma unroll
    for (int t = 0; t < 10; ++t) if (lane + 64 * t < MF) m = fmaxf(m, vv[t]);
#pragma unroll
    for (int mk = 1; mk <= 32; mk <<= 1) m = fmaxf(m, __shfl_xor(m, mk, 64));
    float d0 = (float)qh[(size_t)r * DH + lane] + (float)ql[(size_t)r * DH + lane];
    float d1 = (float)qh[(size_t)r * DH + 64 + lane] + (float)ql[(size_t)r * DH + 64 + lane];
    float dsq = d0 * d0 + d1 * d1;
#pragma unroll
    for (int mk = 1; mk <= 32; mk <<= 1) dsq += __shfl_xor(dsq, mk, 64);
    const float sub = (0.5f * DN2) * dsq + m;
    float s0 = 0, s1 = 0, s2 = 0, s3 = 0, s4 = 0;
#pragma unroll
    for (int t = 0; t < 10; ++t) {
      const int c = lane + 64 * t;
      const float qfv = RATIO * (__expf(vv[t] - sub) + EPS);
      s0 += qfv * rfs[0][c]; s1 += qfv * rfs[1][c]; s2 += qfv * rfs[2][c];
      s3 += qfv * rfs[3][c]; s4 += qfv * rfs[4][c];
    }
#pragma unroll
    for (int mk = 1; mk <= 32; mk <<= 1) {
      s0 += __shfl_xor(s0, mk, 64); s1 += __shfl_xor(s1, mk, 64);
      s2 += __shfl_xor(s2, mk, 64); s3 += __shfl_xor(s3, mk, 64);
      s4 += __shfl_xor(s4, mk, 64);
    }
    if (lane == 0) {
      float* f = fd + (size_t)r * 8;
      f[0] = s0; f[1] = s1; f[2] = s2; f[3] = s3; f[4] = s4;
    }
  }
}

// ---------- gather + normalize + bf16-split of attn ----------
__global__ __launch_bounds__(256) void out_kernel(const float* __restrict__ fd,
                                                  const float* __restrict__ v,
                                                  const float* __restrict__ vsum,
                                                  bf16_t* __restrict__ attnh,
                                                  bf16_t* __restrict__ attnl) {
  const int tid = threadIdx.x;
  const int sub = tid >> 7, d = tid & 127;
  const int bh = blockIdx.y, b = bh >> 3, h = bh & 7;
  const int l = blockIdx.x * 2 + sub;
  if (l >= L) return;
  const size_t r = (size_t)(b * L + l) * H + h;
  const float q0 = fd[r * 8 + 0], q1 = fd[r * 8 + 1], q2 = fd[r * 8 + 2],
              q3 = fd[r * 8 + 3], sM = fd[r * 8 + 4];
  float o = sM * vsum[(size_t)bh * DH + d];
  float c0 = 0, c1 = 0, c2 = 0, c3 = 0;
  const int xo = (l < 100) ? (l % 10) : 0;
  const int yo = (l < 100) ? (l / 10) : 10;
#pragma unroll
  for (int k = 0; k < 49; ++k) {
    const int dx = (k % 7) - 3, dy = (k / 7) - 3;
    const int xp = xo + dx, yp = yo + dy;
    const int df = (dx < 0 ? -dx : dx) + (dy < 0 ? -dy : dy);
    if (xp >= 0 && xp < 10 && yp >= 0 && yp < 10 && df < 4) {
      float qq;
      if (df == 0)      { c0 += 1.f; qq = q0; }
      else if (df == 1) { c1 += 1.f; qq = q1; }
      else if (df == 2) { c2 += 1.f; qq = q2; }
      else              { c3 += 1.f; qq = q3; }
      const int pos = l + dx + 10 * dy;
      o += qq * v[(size_t)(b * L + pos) * DIM + h * DH + d];
    }
  }
  const float D = c0 * q0 + c1 * q1 + c2 * q2 + c3 * q3 + (float)L * sM;
  const float val = o / D;
  bf16_t hi, lo; split2(val, hi, lo);
  const size_t oi = (size_t)(b * L + l) * DIM + h * DH + d;
  attnh[oi] = hi;
  attnl[oi] = lo;
}

}  // namespace

extern "C" void kernel_launch(void* const* d_in, const int* in_sizes, int n_in,
                              void* d_out, int out_size, void* d_ws, size_t ws_size,
                              hipStream_t stream) {
  const float* x    = (const float*)d_in[0];
  const float* Wq   = (const float*)d_in[1];
  const float* bq   = (const float*)d_in[2];
  const float* Wv   = (const float*)d_in[3];
  const float* bv   = (const float*)d_in[4];
  const float* rpe  = (const float*)d_in[5];
  const float* proj = (const float*)d_in[6];
  const float* Wo   = (const float*)d_in[7];
  const float* bo   = (const float*)d_in[8];

  char* p = (char*)d_ws;
  auto alloc = [&](size_t bytes) { char* r = p; p += (bytes + 255) & ~255ull; return r; };
  bf16_t* xh  = (bf16_t*)alloc((size_t)BLP * DIM * 2);
  bf16_t* xl  = (bf16_t*)alloc((size_t)BLP * DIM * 2);
  bf16_t* Wh  = (bf16_t*)alloc((size_t)2 * DIM * DIM * 2);  // Wq rows 0..1023, Wv rows 1024..2047
  bf16_t* Woh = (bf16_t*)alloc((size_t)DIM * DIM * 2);
  bf16_t* ph  = (bf16_t*)alloc((size_t)MFP * DH * 2);
  bf16_t* rh  = (bf16_t*)alloc((size_t)64 * DH * 2);
  bf16_t* rl  = (bf16_t*)alloc((size_t)64 * DH * 2);
  bf16_t* qh  = (bf16_t*)alloc((size_t)BLP * DIM * 2);   // q, later attn
  bf16_t* ql  = (bf16_t*)alloc((size_t)BLP * DIM * 2);
  float*  v   = (float*)alloc((size_t)BL * DIM * 4);
  float*  dd  = (float*)alloc((size_t)(RR + 64) * MFP * 4);
  float*  fd  = (float*)alloc((size_t)RR * 8 * 4);
  float*  vsm = (float*)alloc((size_t)BH * DH * 4);

  split_all<<<(NTOT + 255) / 256, 256, 0, stream>>>(x, proj, rpe, Wq, Wv, Wo,
                                                    xh, xl, ph, rh, rl,
                                                    Wh, Woh, qh, ql);
  // fused q+v projection: N=2048, 2-term, BK=64 (416 blocks)
  gemm64<1><<<dim3(32, 13), 256, 0, stream>>>(xh, xl, Wh, bq, bv, v, qh, ql);
  // dd GEMM: 2-term, K=128, tile 32x64 (2040 blocks); y>=202 -> rf rows
  dd_gemm<<<dim3(10, 204), 256, 0, stream>>>(qh, ql, rh, rl, ph, dd);
  qf2_kernel<<<808 + 32, 256, 0, stream>>>(dd, qh, ql, rpe, v, vsm, fd);
  out_kernel<<<dim3((L + 1) / 2, BH), 256, 0, stream>>>(fd, v, vsm, qh, ql);
  // output projection: 2-term, BK=64 (208 blocks)
  gemm64<0><<<dim3(16, 13), 256, 0, stream>>>(qh, ql, Woh, bo, nullptr,
                                              (float*)d_out, nullptr, nullptr);
}

// Round 10
// 76.948 us; speedup vs baseline: 1.1715x; 1.1058x over previous
//
#include <hip/hip_runtime.h>
#include <math.h>

namespace {

typedef __bf16 bf16_t;
typedef bf16_t bf16x8 __attribute__((ext_vector_type(8)));
typedef bf16_t bf16x4 __attribute__((ext_vector_type(4)));
typedef float f32x4 __attribute__((ext_vector_type(4)));

constexpr int B = 8, L = 101, DIM = 1024, H = 8, DH = 128, MF = 621, MFP = 640;
constexpr int BL = B * L;    // 808
constexpr int BLP = 832;     // padded rows for GEMM A
constexpr int BH = B * H;    // 64
constexpr int RR = BL * H;   // 6464

constexpr float DN    = 0.29730177875068026f;   // 128^-0.25
constexpr float DN2   = 0.08838834764831845f;   // 128^-0.5
constexpr float RATIO = 0.04012861672f;         // 621^-0.5
constexpr float EPS   = 1e-4f;

// split_all segment sizes (bf16x4 / float4 units)
constexpr int NX = BL * DIM / 4;    // 206848
constexpr int NP = MFP * 32;        // 20480  (proj -> ph only)
constexpr int NR = 64 * DH / 4;     // 2048   (rpe, padded to 64 rows, split)
constexpr int NW = DIM * DIM / 4;   // 262144
constexpr int NZ = 4 * (BLP - BL) * DIM / 4;  // 24576 pad-zero units (xh,xl,qh,ql)
constexpr int NTOT = NX + NP + NR + 3 * NW + NZ;

__device__ __forceinline__ f32x4 mfma16(bf16x8 a, bf16x8 b, f32x4 c) {
  return __builtin_amdgcn_mfma_f32_16x16x32_bf16(a, b, c, 0, 0, 0);
}

__device__ __forceinline__ void split2(float f, bf16_t& h, bf16_t& l) {
  h = (bf16_t)f;
  l = (bf16_t)(f - (float)h);
}

__device__ __forceinline__ void gload_lds16(const bf16_t* g, bf16_t* l) {
  __builtin_amdgcn_global_load_lds(
      (const __attribute__((address_space(1))) void*)g,
      (__attribute__((address_space(3))) void*)l, 16, 0, 0);
}

// ---------- one-shot convert/split of everything ----------
__global__ __launch_bounds__(256) void split_all(const float* __restrict__ x,
                                                 const float* __restrict__ proj,
                                                 const float* __restrict__ rpe,
                                                 const float* __restrict__ Wq,
                                                 const float* __restrict__ Wv,
                                                 const float* __restrict__ Wo,
                                                 bf16_t* __restrict__ xh, bf16_t* __restrict__ xl,
                                                 bf16_t* __restrict__ ph,
                                                 bf16_t* __restrict__ rh, bf16_t* __restrict__ rl,
                                                 bf16_t* __restrict__ Wh,
                                                 bf16_t* __restrict__ Woh,
                                                 bf16_t* __restrict__ qh, bf16_t* __restrict__ ql) {
  const int u = blockIdx.x * 256 + threadIdx.x;
  if (u >= NTOT) return;
  auto emit2 = [](const float* s4, float sc, bf16_t* dh, bf16_t* dl, size_t off) {
    float4 f = *(const float4*)s4;
    bf16x4 hv, lv; bf16_t h, l;
    split2(f.x * sc, h, l); hv[0] = h; lv[0] = l;
    split2(f.y * sc, h, l); hv[1] = h; lv[1] = l;
    split2(f.z * sc, h, l); hv[2] = h; lv[2] = l;
    split2(f.w * sc, h, l); hv[3] = h; lv[3] = l;
    *(bf16x4*)(dh + off) = hv;
    *(bf16x4*)(dl + off) = lv;
  };
  auto emit1 = [](const float* s4, float sc, bf16_t* dh, size_t off) {
    float4 f = *(const float4*)s4;
    bf16x4 hv;
    hv[0] = (bf16_t)(f.x * sc); hv[1] = (bf16_t)(f.y * sc);
    hv[2] = (bf16_t)(f.z * sc); hv[3] = (bf16_t)(f.w * sc);
    *(bf16x4*)(dh + off) = hv;
  };
  int t = u;
  if (t < NX) { emit2(x + (size_t)t * 4, 1.f, xh, xl, (size_t)t * 4); return; }
  t -= NX;
  if (t < NP) {
    if ((t >> 5) < MF) emit1(proj + (size_t)t * 4, DN, ph, (size_t)t * 4);
    else { bf16x4 z = {}; *(bf16x4*)(ph + (size_t)t * 4) = z; }
    return;
  }
  t -= NP;
  if (t < NR) {
    if (t < 5 * DH / 4) emit2(rpe + (size_t)t * 4, 1.f, rh, rl, (size_t)t * 4);
    else { bf16x4 z = {}; *(bf16x4*)(rh + (size_t)t * 4) = z; *(bf16x4*)(rl + (size_t)t * 4) = z; }
    return;
  }
  t -= NR;
  if (t < NW) { emit1(Wq + (size_t)t * 4, 1.f, Wh, (size_t)t * 4); return; }
  t -= NW;
  if (t < NW) { emit1(Wv + (size_t)t * 4, 1.f, Wh, (size_t)(t + NW) * 4); return; }
  t -= NW;
  if (t < NW) { emit1(Wo + (size_t)t * 4, 1.f, Woh, (size_t)t * 4); return; }
  t -= NW;
  {  // zero pads rows 808..831 of xh,xl,qh,ql
    const int buf = t / 6144, o = t % 6144;
    bf16_t* dst = (buf == 0) ? xh : (buf == 1) ? xl : (buf == 2) ? qh : ql;
    bf16x4 z = {};
    *(bf16x4*)(dst + (size_t)BL * DIM + (size_t)o * 4) = z;
  }
}

// ---------- BK=64 LDS-staged 2-term MFMA GEMM, block tile 64x64, 4 waves 32x32 ----------
template<int MODE>
__global__ __launch_bounds__(256) void gemm64(const bf16_t* __restrict__ Ah,
                                              const bf16_t* __restrict__ Al,
                                              const bf16_t* __restrict__ Bh,
                                              const float* __restrict__ bias0,
                                              const float* __restrict__ bias1,
                                              float* __restrict__ Cf,
                                              bf16_t* __restrict__ Ch,
                                              bf16_t* __restrict__ Cl) {
  constexpr int K = 1024, BK = 64, NK = K / BK;   // 16 steps
  __shared__ bf16_t lds[2][3][64 * 64];           // [dbuf][Ah,Al,B]
  const int tid = threadIdx.x;
  const int w = tid >> 6, lane = tid & 63;
  const int wr = w >> 1, wc = w & 1;
  const int l15 = lane & 15, l4 = lane >> 4;
  const int rowBase = blockIdx.y * 64, colBase = blockIdx.x * 64;
  const int r8 = lane >> 3;                 // 0..7
  const int cs = (lane & 7) ^ r8;           // pre-swizzled source col16 group
  const bf16_t* src = (w == 0) ? Ah : (w == 1) ? Al : Bh;
  const int grow0 = (w < 2) ? rowBase : colBase + ((w == 3) ? 32 : 0);
  const bf16_t* srcL = src + (size_t)(grow0 + r8) * K + cs * 8;
  const int tt = (w < 2) ? w : 2;
  const int dst0 = (w == 3) ? 32 * 64 : 0;
  auto STAGE = [&](int bf, int k0) {
    if (w < 2) {
#pragma unroll
      for (int j = 0; j < 8; ++j)
        gload_lds16(srcL + (size_t)(8 * j) * K + k0, &lds[bf][tt][j * 512]);
    } else {
#pragma unroll
      for (int j = 0; j < 4; ++j)
        gload_lds16(srcL + (size_t)(8 * j) * K + k0, &lds[bf][2][dst0 + j * 512]);
    }
  };
  const int ra0 = wr * 32 + l15, ra1 = ra0 + 16;
  const int rb0 = wc * 32 + l15, rb1 = rb0 + 16;
  auto TADDR = [](int row, int kg) { return row * 64 + (((kg) ^ (row & 7)) << 3); };
  f32x4 acc[2][2] = {};
  STAGE(0, 0);
  __syncthreads();
  int bf = 0;
  for (int ks = 0; ks < NK; ++ks) {
    if (ks + 1 < NK) STAGE(bf ^ 1, (ks + 1) * BK);
#pragma unroll
    for (int subk = 0; subk < 2; ++subk) {
      const int kg = subk * 4 + l4;
      bf16x8 a0h = *(const bf16x8*)&lds[bf][0][TADDR(ra0, kg)];
      bf16x8 a0l = *(const bf16x8*)&lds[bf][1][TADDR(ra0, kg)];
      bf16x8 a1h = *(const bf16x8*)&lds[bf][0][TADDR(ra1, kg)];
      bf16x8 a1l = *(const bf16x8*)&lds[bf][1][TADDR(ra1, kg)];
      bf16x8 b0  = *(const bf16x8*)&lds[bf][2][TADDR(rb0, kg)];
      bf16x8 b1  = *(const bf16x8*)&lds[bf][2][TADDR(rb1, kg)];
      acc[0][0] = mfma16(a0h, b0, acc[0][0]);
      acc[0][0] = mfma16(a0l, b0, acc[0][0]);
      acc[0][1] = mfma16(a0h, b1, acc[0][1]);
      acc[0][1] = mfma16(a0l, b1, acc[0][1]);
      acc[1][0] = mfma16(a1h, b0, acc[1][0]);
      acc[1][0] = mfma16(a1l, b0, acc[1][0]);
      acc[1][1] = mfma16(a1h, b1, acc[1][1]);
      acc[1][1] = mfma16(a1l, b1, acc[1][1]);
    }
    __syncthreads();
    bf ^= 1;
  }
#pragma unroll
  for (int ni = 0; ni < 2; ++ni) {
    const int col = colBase + wc * 32 + ni * 16 + l15;
#pragma unroll
    for (int mi = 0; mi < 2; ++mi) {
#pragma unroll
      for (int r2 = 0; r2 < 4; ++r2) {
        const int row = rowBase + wr * 32 + mi * 16 + l4 * 4 + r2;
        if (row < BL) {
          if (MODE == 0) {
            Cf[(size_t)row * 1024 + col] = acc[mi][ni][r2] + bias0[col];
          } else {
            if (col < 1024) {
              float val = acc[mi][ni][r2] + bias0[col];
              bf16_t h, lo; split2(val, h, lo);
              Ch[(size_t)row * 1024 + col] = h;
              Cl[(size_t)row * 1024 + col] = lo;
            } else {
              Cf[(size_t)row * 1024 + (col - 1024)] = acc[mi][ni][r2] + bias1[col - 1024];
            }
          }
        }
      }
    }
  }
}

// ---------- qf3: fused dd-GEMM (in-register) + rf + maxes + exp + 5 reductions ----------
// Block = 32 q-rows x 640 cols. A (32 q + 32 rf rows, h+l) staged once; B (ph) streamed
// in 10 dbuf 64x128 chunks. Wave w owns cols {64c + 16w + l15}. Blocks >= 202 do vsum.
__global__ __launch_bounds__(256) void qf3_kernel(const bf16_t* __restrict__ qh,
                                                  const bf16_t* __restrict__ ql,
                                                  const bf16_t* __restrict__ rh,
                                                  const bf16_t* __restrict__ rl,
                                                  const bf16_t* __restrict__ ph,
                                                  const float* __restrict__ rpe,
                                                  const float* __restrict__ v,
                                                  float* __restrict__ vsum,
                                                  float* __restrict__ fd) {
  const int tid = threadIdx.x;
  if (blockIdx.x >= 202) {   // vsum blocks: 32 blocks x 2 bh each
    const int bi = blockIdx.x - 202;
    const int half = tid >> 7, d = tid & 127;
    const int bh = bi * 2 + half;
    const int b = bh >> 3, h = bh & 7;
    const float* base = v + (size_t)(b * L) * DIM + h * DH + d;
    float s0 = 0.f, s1 = 0.f, s2 = 0.f, s3 = 0.f;
    int l = 0;
    for (; l + 4 <= L; l += 4) {
      s0 += base[(size_t)l * DIM];
      s1 += base[(size_t)(l + 1) * DIM];
      s2 += base[(size_t)(l + 2) * DIM];
      s3 += base[(size_t)(l + 3) * DIM];
    }
    for (; l < L; ++l) s0 += base[(size_t)l * DIM];
    vsum[(size_t)bh * DH + d] = s0 + s1 + s2 + s3;
    return;
  }
  __shared__ bf16_t Ahl[2][64 * 128];   // [h,l][row*128+col16*8]; rows 0..31 q, 32..63 rf(pad)
  __shared__ bf16_t Bch[2][64 * 128];   // [dbuf] chunk of ph
  __shared__ float rfs[5][MFP];
  __shared__ float diag[32];
  __shared__ float diag5v[8];
  __shared__ float mxs[4][32];
  __shared__ float mxAll[32];
  __shared__ float mxrf[4];
  __shared__ float sred[4][32][5];
  const int w = tid >> 6, lane = tid & 63;
  const int l15 = lane & 15, l4 = lane >> 4;
  const int r0 = blockIdx.x * 32;
  // staging lane decomposition: 4 rows x 16 col16-groups per instr
  const int r4 = lane >> 4;        // 0..3 (row within 4-row group)
  const int cg = lane & 15;        // dest col16
  // ---- A stage (once): w0:qh rows 0..31, w1:ql 0..31, w2:rh->rows 32..63, w3:rl ----
  {
    const bf16_t* srcA = (w == 0) ? qh : (w == 1) ? ql : (w == 2) ? rh : rl;
    const int arow0 = (w < 2) ? r0 : 0;
    bf16_t* dstA = &Ahl[w & 1][(w >= 2 ? 32 : 0) * 128];
    const bf16_t* peA = srcA + (size_t)(arow0 + r4) * DH + ((cg ^ r4) << 3);
    const bf16_t* poA = srcA + (size_t)(arow0 + r4) * DH + ((cg ^ r4 ^ 4) << 3);
#pragma unroll
    for (int j = 0; j < 8; ++j)
      gload_lds16(((j & 1) ? poA : peA) + (size_t)(4 * j) * DH, dstA + j * 512);
  }
  // ---- B chunk stage: wave w stages rows w*16..w*16+15 of the 64-row chunk ----
  const bf16_t* peB = ph + (size_t)(w * 16 + r4) * DH + ((cg ^ r4) << 3);
  const bf16_t* poB = ph + (size_t)(w * 16 + r4) * DH + ((cg ^ r4 ^ 4) << 3);
  auto STAGE_B = [&](int buf, int c) {
    const size_t coff = (size_t)c * 64 * DH;
#pragma unroll
    for (int j = 0; j < 4; ++j)
      gload_lds16(((j & 1) ? poB : peB) + coff + (size_t)(4 * j) * DH,
                  &Bch[buf][(w * 16 + j * 4) * 128]);
  };
  // ---- diag (q rows) and diag5v (rpe rows) ----
  {
    const int row = tid >> 3, ch = tid & 7;
    const size_t base = (size_t)(r0 + row) * DH + ch * 16;
    float s = 0.f;
#pragma unroll
    for (int t = 0; t < 2; ++t) {
      bf16x8 vh = *(const bf16x8*)(qh + base + t * 8);
      bf16x8 vl = *(const bf16x8*)(ql + base + t * 8);
#pragma unroll
      for (int e = 0; e < 8; ++e) {
        float f = (float)vh[e] + (float)vl[e];
        s += f * f;
      }
    }
    s += __shfl_xor(s, 1, 64); s += __shfl_xor(s, 2, 64); s += __shfl_xor(s, 4, 64);
    if (ch == 0) diag[row] = (0.5f * DN2) * s;
  }
  if (tid < 40) {
    const int row = tid >> 3, ch = tid & 7;
    float s = 0.f;
#pragma unroll
    for (int e = 0; e < 16; ++e) { float f = rpe[row * DH + ch * 16 + e]; s += f * f; }
    s += __shfl_xor(s, 1, 64); s += __shfl_xor(s, 2, 64); s += __shfl_xor(s, 4, 64);
    if (ch == 0) diag5v[row] = (0.5f * DN2) * s;
  }
  // ---- main loop: 10 chunks, 4 k-steps each ----
  auto TADDR = [](int row, int kg) { return row * 128 + (((kg) ^ (row & 7)) << 3); };
  f32x4 acc[2][10] = {};
  f32x4 accr[10] = {};
  STAGE_B(0, 0);
  __syncthreads();
  int buf = 0;
#pragma unroll
  for (int c = 0; c < 10; ++c) {
    if (c + 1 < 10) STAGE_B(buf ^ 1, c + 1);
#pragma unroll
    for (int ks = 0; ks < 4; ++ks) {
      const int kg = ks * 4 + l4;
      bf16x8 a0h = *(const bf16x8*)&Ahl[0][TADDR(l15, kg)];
      bf16x8 a0l = *(const bf16x8*)&Ahl[1][TADDR(l15, kg)];
      bf16x8 a1h = *(const bf16x8*)&Ahl[0][TADDR(16 + l15, kg)];
      bf16x8 a1l = *(const bf16x8*)&Ahl[1][TADDR(16 + l15, kg)];
      bf16x8 arh = *(const bf16x8*)&Ahl[0][TADDR(32 + l15, kg)];
      bf16x8 arl = *(const bf16x8*)&Ahl[1][TADDR(32 + l15, kg)];
      bf16x8 bb  = *(const bf16x8*)&Bch[buf][TADDR(w * 16 + l15, kg)];
      acc[0][c] = mfma16(a0h, bb, acc[0][c]);
      acc[0][c] = mfma16(a0l, bb, acc[0][c]);
      acc[1][c] = mfma16(a1h, bb, acc[1][c]);
      acc[1][c] = mfma16(a1l, bb, acc[1][c]);
      accr[c]   = mfma16(arh, bb, accr[c]);
      accr[c]   = mfma16(arl, bb, accr[c]);
    }
    __syncthreads();
    buf ^= 1;
  }
  // ---- q per-row max over this wave's cols ----
  float pm[2][4];
#pragma unroll
  for (int mi = 0; mi < 2; ++mi)
#pragma unroll
    for (int r2 = 0; r2 < 4; ++r2) {
      float m = -3.4e38f;
#pragma unroll
      for (int ni = 0; ni < 10; ++ni) {
        const int col = ni * 64 + w * 16 + l15;
        float vv = (col < MF) ? acc[mi][ni][r2] : -3.4e38f;
        m = fmaxf(m, vv);
      }
      pm[mi][r2] = m;
    }
#pragma unroll
  for (int mask = 1; mask <= 8; mask <<= 1)
#pragma unroll
    for (int mi = 0; mi < 2; ++mi)
#pragma unroll
      for (int r2 = 0; r2 < 4; ++r2)
        pm[mi][r2] = fmaxf(pm[mi][r2], __shfl_xor(pm[mi][r2], mask, 64));
  if (l15 == 0) {
#pragma unroll
    for (int mi = 0; mi < 2; ++mi)
#pragma unroll
      for (int r2 = 0; r2 < 4; ++r2)
        mxs[w][mi * 16 + l4 * 4 + r2] = pm[mi][r2];
  }
  // ---- rf global max ----
  {
    float m = -3.4e38f;
#pragma unroll
    for (int ni = 0; ni < 10; ++ni) {
      const int col = ni * 64 + w * 16 + l15;
#pragma unroll
      for (int r2 = 0; r2 < 4; ++r2) {
        const int row5 = l4 * 4 + r2;
        if (row5 < 5 && col < MF) m = fmaxf(m, accr[ni][r2]);
      }
    }
#pragma unroll
    for (int mask = 1; mask <= 32; mask <<= 1) m = fmaxf(m, __shfl_xor(m, mask, 64));
    if (lane == 0) mxrf[w] = m;
  }
  __syncthreads();
  // ---- rf exp -> rfs; cross-wave q max ----
  {
    const float mxR = fmaxf(fmaxf(mxrf[0], mxrf[1]), fmaxf(mxrf[2], mxrf[3]));
#pragma unroll
    for (int ni = 0; ni < 10; ++ni) {
      const int col = ni * 64 + w * 16 + l15;
#pragma unroll
      for (int r2 = 0; r2 < 4; ++r2) {
        const int row5 = l4 * 4 + r2;
        if (row5 < 5) {
          float val = (col < MF)
              ? RATIO * (__expf(accr[ni][r2] - diag5v[row5] - mxR) + EPS) : 0.f;
          rfs[row5][col] = val;
        }
      }
    }
  }
  if (tid < 32)
    mxAll[tid] = fmaxf(fmaxf(mxs[0][tid], mxs[1][tid]), fmaxf(mxs[2][tid], mxs[3][tid]));
  __syncthreads();
  for (int i = tid; i < 4 * MFP; i += 256) rfs[i / MFP][i % MFP] -= rfs[4][i % MFP];
  __syncthreads();
  // ---- qf exp + 5 weighted sums ----
  float s[2][4][5] = {};
#pragma unroll
  for (int mi = 0; mi < 2; ++mi)
#pragma unroll
    for (int r2 = 0; r2 < 4; ++r2) {
      const int row = mi * 16 + l4 * 4 + r2;
      const float sub = diag[row] + mxAll[row];
#pragma unroll
      for (int ni = 0; ni < 10; ++ni) {
        const int col = ni * 64 + w * 16 + l15;
        const float qfv = RATIO * (__expf(acc[mi][ni][r2] - sub) + EPS);
#pragma unroll
        for (int c = 0; c < 5; ++c) s[mi][r2][c] += qfv * rfs[c][col];
      }
    }
#pragma unroll
  for (int mask = 1; mask <= 8; mask <<= 1)
#pragma unroll
    for (int mi = 0; mi < 2; ++mi)
#pragma unroll
      for (int r2 = 0; r2 < 4; ++r2)
#pragma unroll
        for (int c = 0; c < 5; ++c)
          s[mi][r2][c] += __shfl_xor(s[mi][r2][c], mask, 64);
  if (l15 == 0) {
#pragma unroll
    for (int mi = 0; mi < 2; ++mi)
#pragma unroll
      for (int r2 = 0; r2 < 4; ++r2)
#pragma unroll
        for (int c = 0; c < 5; ++c)
          sred[w][mi * 16 + l4 * 4 + r2][c] = s[mi][r2][c];
  }
  __syncthreads();
  if (tid < 160) {
    const int row = tid / 5, c = tid % 5;
    fd[(size_t)(r0 + row) * 8 + c] =
        sred[0][row][c] + sred[1][row][c] + sred[2][row][c] + sred[3][row][c];
  }
}

// ---------- gather + normalize + bf16-split of attn ----------
__global__ __launch_bounds__(256) void out_kernel(const float* __restrict__ fd,
                                                  const float* __restrict__ v,
                                                  const float* __restrict__ vsum,
                                                  bf16_t* __restrict__ attnh,
                                                  bf16_t* __restrict__ attnl) {
  const int tid = threadIdx.x;
  const int sub = tid >> 7, d = tid & 127;
  const int bh = blockIdx.y, b = bh >> 3, h = bh & 7;
  const int l = blockIdx.x * 2 + sub;
  if (l >= L) return;
  const size_t r = (size_t)(b * L + l) * H + h;
  const float q0 = fd[r * 8 + 0], q1 = fd[r * 8 + 1], q2 = fd[r * 8 + 2],
              q3 = fd[r * 8 + 3], sM = fd[r * 8 + 4];
  float o = sM * vsum[(size_t)bh * DH + d];
  float c0 = 0, c1 = 0, c2 = 0, c3 = 0;
  const int xo = (l < 100) ? (l % 10) : 0;
  const int yo = (l < 100) ? (l / 10) : 10;
#pragma unroll
  for (int k = 0; k < 49; ++k) {
    const int dx = (k % 7) - 3, dy = (k / 7) - 3;
    const int xp = xo + dx, yp = yo + dy;
    const int df = (dx < 0 ? -dx : dx) + (dy < 0 ? -dy : dy);
    if (xp >= 0 && xp < 10 && yp >= 0 && yp < 10 && df < 4) {
      float qq;
      if (df == 0)      { c0 += 1.f; qq = q0; }
      else if (df == 1) { c1 += 1.f; qq = q1; }
      else if (df == 2) { c2 += 1.f; qq = q2; }
      else              { c3 += 1.f; qq = q3; }
      const int pos = l + dx + 10 * dy;
      o += qq * v[(size_t)(b * L + pos) * DIM + h * DH + d];
    }
  }
  const float D = c0 * q0 + c1 * q1 + c2 * q2 + c3 * q3 + (float)L * sM;
  const float val = o / D;
  bf16_t hi, lo; split2(val, hi, lo);
  const size_t oi = (size_t)(b * L + l) * DIM + h * DH + d;
  attnh[oi] = hi;
  attnl[oi] = lo;
}

}  // namespace

extern "C" void kernel_launch(void* const* d_in, const int* in_sizes, int n_in,
                              void* d_out, int out_size, void* d_ws, size_t ws_size,
                              hipStream_t stream) {
  const float* x    = (const float*)d_in[0];
  const float* Wq   = (const float*)d_in[1];
  const float* bq   = (const float*)d_in[2];
  const float* Wv   = (const float*)d_in[3];
  const float* bv   = (const float*)d_in[4];
  const float* rpe  = (const float*)d_in[5];
  const float* proj = (const float*)d_in[6];
  const float* Wo   = (const float*)d_in[7];
  const float* bo   = (const float*)d_in[8];

  char* p = (char*)d_ws;
  auto alloc = [&](size_t bytes) { char* r = p; p += (bytes + 255) & ~255ull; return r; };
  bf16_t* xh  = (bf16_t*)alloc((size_t)BLP * DIM * 2);
  bf16_t* xl  = (bf16_t*)alloc((size_t)BLP * DIM * 2);
  bf16_t* Wh  = (bf16_t*)alloc((size_t)2 * DIM * DIM * 2);  // Wq rows 0..1023, Wv rows 1024..2047
  bf16_t* Woh = (bf16_t*)alloc((size_t)DIM * DIM * 2);
  bf16_t* ph  = (bf16_t*)alloc((size_t)MFP * DH * 2);
  bf16_t* rh  = (bf16_t*)alloc((size_t)64 * DH * 2);
  bf16_t* rl  = (bf16_t*)alloc((size_t)64 * DH * 2);
  bf16_t* qh  = (bf16_t*)alloc((size_t)BLP * DIM * 2);   // q, later attn
  bf16_t* ql  = (bf16_t*)alloc((size_t)BLP * DIM * 2);
  float*  v   = (float*)alloc((size_t)BL * DIM * 4);
  float*  fd  = (float*)alloc((size_t)RR * 8 * 4);
  float*  vsm = (float*)alloc((size_t)BH * DH * 4);

  split_all<<<(NTOT + 255) / 256, 256, 0, stream>>>(x, proj, rpe, Wq, Wv, Wo,
                                                    xh, xl, ph, rh, rl,
                                                    Wh, Woh, qh, ql);
  // fused q+v projection: N=2048, 2-term, BK=64 (416 blocks)
  gemm64<1><<<dim3(32, 13), 256, 0, stream>>>(xh, xl, Wh, bq, bv, v, qh, ql);
  // fused dd + feature reductions + vsum (202 + 32 blocks)
  qf3_kernel<<<202 + 32, 256, 0, stream>>>(qh, ql, rh, rl, ph, rpe, v, vsm, fd);
  out_kernel<<<dim3((L + 1) / 2, BH), 256, 0, stream>>>(fd, v, vsm, qh, ql);
  // output projection: 2-term, BK=64 (208 blocks)
  gemm64<0><<<dim3(16, 13), 256, 0, stream>>>(qh, ql, Woh, bo, nullptr,
                                              (float*)d_out, nullptr, nullptr);
}